// Round 1
// baseline (549.533 us; speedup 1.0000x reference)
//
#include <hip/hip_runtime.h>
#include <hip/hip_bf16.h>
#include <stdint.h>

typedef __bf16 bf16_t;
typedef __bf16 bf16x4v __attribute__((ext_vector_type(4)));
typedef __bf16 bf16x8v __attribute__((ext_vector_type(8)));
typedef float f32x4v __attribute__((ext_vector_type(4)));

#define DEVI static __device__ __forceinline__

// Problem constants
// B=4, T=2048, D=1024, H=16, Hd=64, BT=8192

DEVI f32x4v mfma16(bf16x8v a, bf16x8v b, f32x4v c) {
  return __builtin_amdgcn_mfma_f32_16x16x32_bf16(a, b, c, 0, 0, 0);
}

DEVI void gload_lds16(const void* g, void* lds) {
  __builtin_amdgcn_global_load_lds(
      (const __attribute__((address_space(1))) uint32_t*)g,
      (__attribute__((address_space(3))) uint32_t*)lds, 16, 0, 0);
}

// ---------------- weight conversion (fold 1/sqrt(Hd)=0.125 into Wq) ----------
__global__ void k_convw(const float* __restrict__ wq, const float* __restrict__ wk,
                        const float* __restrict__ wv, const float* __restrict__ wo,
                        bf16_t* __restrict__ out) {
  int i = blockIdx.x * 256 + threadIdx.x;  // quad index; 4*1M elems = 1M quads
  int m = i >> 18;                         // which matrix (262144 quads each)
  int off = (i & 0x3FFFF) << 2;
  const float* src = (m == 0) ? wq : (m == 1) ? wk : (m == 2) ? wv : wo;
  float4 v = *(const float4*)(src + off);
  float s = (m == 0) ? 0.125f : 1.0f;
  bf16x4v r;
  r[0] = (bf16_t)(v.x * s);
  r[1] = (bf16_t)(v.y * s);
  r[2] = (bf16_t)(v.z * s);
  r[3] = (bf16_t)(v.w * s);
  *(bf16x4v*)(out + ((size_t)i << 2)) = r;
}

// ---------------- QKV projection GEMM ---------------------------------------
// out[m,n] = sum_k X[m,k] * W[n,k]; M=8192, N=1024, K=1024.
// 128x128 tile, BK=32, 4 waves (each 64x64 = 4x4 frags of 16x16x32).
// A (fp32) reg-staged + converted; B (bf16) via global_load_lds.
// Output written to (B,H,T,Hd) = ((b*16+h)*2048+t)*64+hd, m=b*2048+t, n=h*64+hd.
__global__ __launch_bounds__(256) void k_qkv(
    const float* __restrict__ q_in, const float* __restrict__ k_in,
    const float* __restrict__ v_in, const bf16_t* __restrict__ wb,
    bf16_t* __restrict__ qb, bf16_t* __restrict__ kb, bf16_t* __restrict__ vb) {
  __shared__ __align__(16) bf16_t As[128 * 32];
  __shared__ __align__(16) bf16_t Bs[128 * 32];

  int p = blockIdx.z;
  const float* X = (p == 0) ? q_in : (p == 1) ? k_in : v_in;
  const bf16_t* W = wb + (size_t)p * (1024 * 1024);
  bf16_t* Out = (p == 0) ? qb : (p == 1) ? kb : vb;

  int n0 = blockIdx.x * 128;
  int m0 = blockIdx.y * 128;
  int tid = threadIdx.x, lane = tid & 63, wid = tid >> 6;
  int wm = wid >> 1, wn = wid & 1;

  f32x4v acc[4][4] = {};

  int arow = tid >> 1, ahalf = tid & 1;  // A staging: row 0..127, 16 floats each
  const float* aptr = X + (size_t)(m0 + arow) * 1024 + ahalf * 16;
  bf16_t* asw = As + arow * 32 + ahalf * 16;

  for (int k0 = 0; k0 < 1024; k0 += 32) {
    // B: async global->LDS, 16B per lane, linear dest
#pragma unroll
    for (int j = 0; j < 2; ++j) {
      int c = (wid * 2 + j) * 64 + lane;  // 16B-chunk index 0..511
      const bf16_t* g = W + (size_t)(n0 + (c >> 2)) * 1024 + k0 + (c & 3) * 8;
      gload_lds16(g, (char*)Bs + (size_t)(wid * 2 + j) * 1024);
    }
    // A: fp32 load + convert + ds_write
    float4 f0 = *(const float4*)(aptr + k0);
    float4 f1 = *(const float4*)(aptr + k0 + 4);
    float4 f2 = *(const float4*)(aptr + k0 + 8);
    float4 f3 = *(const float4*)(aptr + k0 + 12);
    bf16x8v t0, t1;
    t0[0] = (bf16_t)f0.x; t0[1] = (bf16_t)f0.y; t0[2] = (bf16_t)f0.z; t0[3] = (bf16_t)f0.w;
    t0[4] = (bf16_t)f1.x; t0[5] = (bf16_t)f1.y; t0[6] = (bf16_t)f1.z; t0[7] = (bf16_t)f1.w;
    t1[0] = (bf16_t)f2.x; t1[1] = (bf16_t)f2.y; t1[2] = (bf16_t)f2.z; t1[3] = (bf16_t)f2.w;
    t1[4] = (bf16_t)f3.x; t1[5] = (bf16_t)f3.y; t1[6] = (bf16_t)f3.z; t1[7] = (bf16_t)f3.w;
    *(bf16x8v*)asw = t0;
    *(bf16x8v*)(asw + 8) = t1;
    __syncthreads();

    bf16x8v af[4], bfv[4];
#pragma unroll
    for (int i = 0; i < 4; ++i)
      af[i] = *(const bf16x8v*)(As + (wm * 64 + i * 16 + (lane & 15)) * 32 + (lane >> 4) * 8);
#pragma unroll
    for (int j = 0; j < 4; ++j)
      bfv[j] = *(const bf16x8v*)(Bs + (wn * 64 + j * 16 + (lane & 15)) * 32 + (lane >> 4) * 8);
#pragma unroll
    for (int i = 0; i < 4; ++i)
#pragma unroll
      for (int j = 0; j < 4; ++j)
        acc[i][j] = mfma16(af[i], bfv[j], acc[i][j]);
    __syncthreads();
  }

  // epilogue: scatter to (B,H,T,Hd) as bf16
#pragma unroll
  for (int i = 0; i < 4; ++i) {
    int mbase = m0 + wm * 64 + i * 16 + ((lane >> 4) << 2);
#pragma unroll
    for (int j = 0; j < 4; ++j) {
      int n = n0 + wn * 64 + j * 16 + (lane & 15);
      int h = n >> 6, hd = n & 63;
#pragma unroll
      for (int r = 0; r < 4; ++r) {
        int m = mbase + r;
        int b = m >> 11, t = m & 2047;
        Out[(((size_t)(b * 16 + h)) * 2048 + t) * 64 + hd] = (bf16_t)acc[i][j][r];
      }
    }
  }
}

// ---------------- causal flash attention ------------------------------------
// grid (T/64, B*H), 4 waves; each wave owns 16 q-rows. KVBLK=32.
// Swapped QK^T: St[k][q] via mfma(Kfrag, Qfrag) -> lane holds one q-row's
// contiguous k-slices; softmax reduce via shfl_xor 16/32.
__global__ __launch_bounds__(256) void k_attn(
    const bf16_t* __restrict__ qb, const bf16_t* __restrict__ kb,
    const bf16_t* __restrict__ vb, bf16_t* __restrict__ ob) {
  __shared__ __align__(16) bf16_t Ks[32 * 72];     // [32 k][64 d] pad->72
  __shared__ __align__(16) bf16_t Vt[64 * 40];     // [64 d][32 k] pad->40
  __shared__ __align__(16) bf16_t Ps[4][16 * 40];  // per-wave P [16 q][32 k] pad->40

  int bh = blockIdx.y;
  int q0 = blockIdx.x * 64;
  int tid = threadIdx.x, lane = tid & 63, w = tid >> 6;

  const bf16_t* Qp = qb + (size_t)bh * 2048 * 64;
  const bf16_t* Kp = kb + (size_t)bh * 2048 * 64;
  const bf16_t* Vp = vb + (size_t)bh * 2048 * 64;

  int qrow = q0 + w * 16 + (lane & 15);  // q-row this lane owns in St layout

  bf16x8v qf[2];
#pragma unroll
  for (int kk = 0; kk < 2; ++kk)
    qf[kk] = *(const bf16x8v*)(Qp + (size_t)qrow * 64 + kk * 32 + (lane >> 4) * 8);

  f32x4v o[4] = {};
  float mrun = -1e30f, lrun = 0.f;

  int kend = q0 + 64;
  for (int k0 = 0; k0 < kend; k0 += 32) {
    // stage K (row-major padded) and V (transposed)
    {
      int r = tid >> 3, c8 = tid & 7;
      bf16x8v kv = *(const bf16x8v*)(Kp + (size_t)(k0 + r) * 64 + c8 * 8);
      *(bf16x8v*)(Ks + r * 72 + c8 * 8) = kv;
      bf16x8v vv = *(const bf16x8v*)(Vp + (size_t)(k0 + r) * 64 + c8 * 8);
#pragma unroll
      for (int j = 0; j < 8; ++j) Vt[(c8 * 8 + j) * 40 + r] = vv[j];
    }
    __syncthreads();

    // QK^T (transposed output): St[k][q]
    f32x4v st[2];
#pragma unroll
    for (int kt = 0; kt < 2; ++kt) {
      f32x4v z = {};
#pragma unroll
      for (int kk = 0; kk < 2; ++kk) {
        bf16x8v kf = *(const bf16x8v*)(Ks + (kt * 16 + (lane & 15)) * 72 + kk * 32 + (lane >> 4) * 8);
        z = mfma16(kf, qf[kk], z);
      }
      st[kt] = z;
    }

    // causal mask + online softmax (4 lanes per q-row: xor 16/32)
    float tmax = -1e30f;
#pragma unroll
    for (int kt = 0; kt < 2; ++kt)
#pragma unroll
      for (int i = 0; i < 4; ++i) {
        int kg = k0 + kt * 16 + ((lane >> 4) << 2) + i;
        float s = (kg > qrow) ? -1e30f : st[kt][i];
        st[kt][i] = s;
        tmax = fmaxf(tmax, s);
      }
    tmax = fmaxf(tmax, __shfl_xor(tmax, 16));
    tmax = fmaxf(tmax, __shfl_xor(tmax, 32));
    float mnew = fmaxf(mrun, tmax);
    float scale = __expf(mrun - mnew);

    float tsum = 0.f;
    bf16x8v pb;
#pragma unroll
    for (int kt = 0; kt < 2; ++kt)
#pragma unroll
      for (int i = 0; i < 4; ++i) {
        float pv = __expf(st[kt][i] - mnew);
        tsum += pv;
        pb[kt * 4 + i] = (bf16_t)pv;
      }
    tsum += __shfl_xor(tsum, 16);
    tsum += __shfl_xor(tsum, 32);
    lrun = lrun * scale + tsum;
    mrun = mnew;

    // write P to per-wave LDS (prev-iter reads already drained)
    asm volatile("s_waitcnt lgkmcnt(0)" ::: "memory");
    bf16_t* pw = &Ps[w][(lane & 15) * 40 + ((lane >> 4) << 2)];
    ((uint64_t*)&pb)[0] = ((uint64_t*)&pb)[0];  // no-op, keep pb addressable
    *(uint64_t*)pw = ((uint64_t*)&pb)[0];        // kt=0: cols 4g..4g+3
    *(uint64_t*)(pw + 16) = ((uint64_t*)&pb)[1]; // kt=1: cols 16+4g..
    asm volatile("s_waitcnt lgkmcnt(0)" ::: "memory");

    // rescale O (O-rows 4g..4g+3; scale held by lanes (4g+i)&15)
#pragma unroll
    for (int i = 0; i < 4; ++i) {
      float sc = __shfl(scale, ((lane >> 4) << 2) + i);
#pragma unroll
      for (int dj = 0; dj < 4; ++dj) o[dj][i] *= sc;
    }

    // PV: A = P [16q x 32k], B = Vt [d x k]
    bf16x8v pa = *(const bf16x8v*)(&Ps[w][(lane & 15) * 40 + (lane >> 4) * 8]);
#pragma unroll
    for (int dj = 0; dj < 4; ++dj) {
      bf16x8v vf = *(const bf16x8v*)(Vt + (dj * 16 + (lane & 15)) * 40 + (lane >> 4) * 8);
      o[dj] = mfma16(pa, vf, o[dj]);
    }
    __syncthreads();
  }

  // epilogue: divide by l, write (B,T,D) bf16
  int b = bh >> 4, h = bh & 15;
  float linv = 1.0f / lrun;
#pragma unroll
  for (int i = 0; i < 4; ++i) {
    float li = __shfl(linv, ((lane >> 4) << 2) + i);
    int t = q0 + w * 16 + ((lane >> 4) << 2) + i;
#pragma unroll
    for (int dj = 0; dj < 4; ++dj)
      ob[((size_t)(b * 2048 + t)) * 1024 + h * 64 + dj * 16 + (lane & 15)] =
          (bf16_t)(o[dj][i] * li);
  }
}

// ---------------- output projection GEMM (+bias, fp32 out) ------------------
__global__ __launch_bounds__(256) void k_oproj(
    const bf16_t* __restrict__ A, const bf16_t* __restrict__ Wo,
    const float* __restrict__ bo, float* __restrict__ out) {
  __shared__ __align__(16) bf16_t As[128 * 32];
  __shared__ __align__(16) bf16_t Bs[128 * 32];

  int n0 = blockIdx.x * 128;
  int m0 = blockIdx.y * 128;
  int tid = threadIdx.x, lane = tid & 63, wid = tid >> 6;
  int wm = wid >> 1, wn = wid & 1;

  f32x4v acc[4][4] = {};

  for (int k0 = 0; k0 < 1024; k0 += 32) {
#pragma unroll
    for (int j = 0; j < 2; ++j) {
      int c = (wid * 2 + j) * 64 + lane;
      gload_lds16(A + (size_t)(m0 + (c >> 2)) * 1024 + k0 + (c & 3) * 8,
                  (char*)As + (size_t)(wid * 2 + j) * 1024);
      gload_lds16(Wo + (size_t)(n0 + (c >> 2)) * 1024 + k0 + (c & 3) * 8,
                  (char*)Bs + (size_t)(wid * 2 + j) * 1024);
    }
    __syncthreads();

    bf16x8v af[4], bfv[4];
#pragma unroll
    for (int i = 0; i < 4; ++i)
      af[i] = *(const bf16x8v*)(As + (wm * 64 + i * 16 + (lane & 15)) * 32 + (lane >> 4) * 8);
#pragma unroll
    for (int j = 0; j < 4; ++j)
      bfv[j] = *(const bf16x8v*)(Bs + (wn * 64 + j * 16 + (lane & 15)) * 32 + (lane >> 4) * 8);
#pragma unroll
    for (int i = 0; i < 4; ++i)
#pragma unroll
      for (int j = 0; j < 4; ++j)
        acc[i][j] = mfma16(af[i], bfv[j], acc[i][j]);
    __syncthreads();
  }

#pragma unroll
  for (int i = 0; i < 4; ++i) {
    int mbase = m0 + wm * 64 + i * 16 + ((lane >> 4) << 2);
#pragma unroll
    for (int j = 0; j < 4; ++j) {
      int n = n0 + wn * 64 + j * 16 + (lane & 15);
      float bias = bo[n];
#pragma unroll
      for (int r = 0; r < 4; ++r) {
        int m = mbase + r;
        out[(size_t)m * 1024 + n] = acc[i][j][r] + bias;
      }
    }
  }
}

// ---------------- launch ----------------------------------------------------
extern "C" void kernel_launch(void* const* d_in, const int* in_sizes, int n_in,
                              void* d_out, int out_size, void* d_ws, size_t ws_size,
                              hipStream_t stream) {
  const float* querys = (const float*)d_in[0];
  const float* keys   = (const float*)d_in[1];
  const float* values = (const float*)d_in[2];
  const float* Wq = (const float*)d_in[3];
  const float* Wk = (const float*)d_in[4];
  const float* Wv = (const float*)d_in[5];
  const float* Wv2 = Wv; (void)Wv2;
  const float* Wo = (const float*)d_in[6];
  const float* bo = (const float*)d_in[7];
  float* out = (float*)d_out;

  char* ws = (char*)d_ws;
  bf16_t* wb = (bf16_t*)ws;                          // 4 x 1M bf16 = 8 MB
  bf16_t* qb = (bf16_t*)(ws + ((size_t)8 << 20));    // 16 MB each
  bf16_t* kb = (bf16_t*)(ws + ((size_t)24 << 20));
  bf16_t* vb = (bf16_t*)(ws + ((size_t)40 << 20));
  bf16_t* ob = (bf16_t*)(ws + ((size_t)56 << 20));   // total 72 MB

  k_convw<<<4096, 256, 0, stream>>>(Wq, Wk, Wv, Wo, wb);
  k_qkv<<<dim3(8, 64, 3), 256, 0, stream>>>(querys, keys, values, wb, qb, kb, vb);
  k_attn<<<dim3(32, 64), 256, 0, stream>>>(qb, kb, vb, ob);
  k_oproj<<<dim3(8, 64), 256, 0, stream>>>(ob, wb + (size_t)3 * 1024 * 1024, bo, out);
}

// Round 2
// 460.144 us; speedup vs baseline: 1.1943x; 1.1943x over previous
//
#include <hip/hip_runtime.h>
#include <hip/hip_bf16.h>
#include <stdint.h>

typedef __bf16 bf16_t;
typedef __bf16 bf16x4v __attribute__((ext_vector_type(4)));
typedef __bf16 bf16x8v __attribute__((ext_vector_type(8)));
typedef float f32x4v __attribute__((ext_vector_type(4)));

#define DEVI static __device__ __forceinline__

// B=4, T=2048, D=1024, H=16, Hd=64

DEVI f32x4v mfma16(bf16x8v a, bf16x8v b, f32x4v c) {
  return __builtin_amdgcn_mfma_f32_16x16x32_bf16(a, b, c, 0, 0, 0);
}

DEVI void gload_lds16(const void* g, void* lds) {
  __builtin_amdgcn_global_load_lds(
      (const __attribute__((address_space(1))) uint32_t*)g,
      (__attribute__((address_space(3))) uint32_t*)lds, 16, 0, 0);
}

DEVI uint32_t pk2(float a, float b) {
  union { bf16_t h[2]; uint32_t u; } r;
  r.h[0] = (bf16_t)a;
  r.h[1] = (bf16_t)b;
  return r.u;
}

// ---------------- weight conversion -----------------------------------------
// Wq gets 0.125 (1/sqrt(64)) * log2(e) folded in (softmax via exp2).
__global__ void k_convw(const float* __restrict__ wq, const float* __restrict__ wk,
                        const float* __restrict__ wv, const float* __restrict__ wo,
                        bf16_t* __restrict__ out) {
  int i = blockIdx.x * 256 + threadIdx.x;
  int m = i >> 18;
  int off = (i & 0x3FFFF) << 2;
  const float* src = (m == 0) ? wq : (m == 1) ? wk : (m == 2) ? wv : wo;
  float4 v = *(const float4*)(src + off);
  float s = (m == 0) ? 0.18033688011112042f : 1.0f;  // 0.125 * log2(e)
  bf16x4v r;
  r[0] = (bf16_t)(v.x * s);
  r[1] = (bf16_t)(v.y * s);
  r[2] = (bf16_t)(v.z * s);
  r[3] = (bf16_t)(v.w * s);
  *(bf16x4v*)(out + ((size_t)i << 2)) = r;
}

// ---------------- QKV projection GEMM ---------------------------------------
// p<2  : C[m][n] = X W^T -> Q/K in (B,H,T,Hd)
// p==2 : operands swapped -> C'[n][m] = V^T in (B,H,Hd,T), coalesced writes
__global__ __launch_bounds__(256) void k_qkv(
    const float* __restrict__ q_in, const float* __restrict__ k_in,
    const float* __restrict__ v_in, const bf16_t* __restrict__ wb,
    bf16_t* __restrict__ qb, bf16_t* __restrict__ kb, bf16_t* __restrict__ vtb) {
  __shared__ __align__(16) bf16_t As[128 * 32];
  __shared__ __align__(16) bf16_t Bs[128 * 32];

  int p = blockIdx.z;
  const float* X = (p == 0) ? q_in : (p == 1) ? k_in : v_in;
  const bf16_t* W = wb + (size_t)p * (1024 * 1024);

  int n0 = blockIdx.x * 128;
  int m0 = blockIdx.y * 128;
  int tid = threadIdx.x, lane = tid & 63, wid = tid >> 6;
  int wm = wid >> 1, wn = wid & 1;

  bf16_t* Xs = (p == 2) ? Bs : As;  // X rows (m-dim) go here
  bf16_t* Ws = (p == 2) ? As : Bs;  // W rows (n-dim) go here

  f32x4v acc[4][4] = {};

  int arow = tid >> 1, ahalf = tid & 1;
  const float* aptr = X + (size_t)(m0 + arow) * 1024 + ahalf * 16;
  bf16_t* asw = Xs + arow * 32 + ahalf * 16;

  for (int k0 = 0; k0 < 1024; k0 += 32) {
#pragma unroll
    for (int j = 0; j < 2; ++j) {
      int c = (wid * 2 + j) * 64 + lane;
      gload_lds16(W + (size_t)(n0 + (c >> 2)) * 1024 + k0 + (c & 3) * 8,
                  (char*)Ws + (size_t)(wid * 2 + j) * 1024);
    }
    float4 f0 = *(const float4*)(aptr + k0);
    float4 f1 = *(const float4*)(aptr + k0 + 4);
    float4 f2 = *(const float4*)(aptr + k0 + 8);
    float4 f3 = *(const float4*)(aptr + k0 + 12);
    bf16x8v t0, t1;
    t0[0] = (bf16_t)f0.x; t0[1] = (bf16_t)f0.y; t0[2] = (bf16_t)f0.z; t0[3] = (bf16_t)f0.w;
    t0[4] = (bf16_t)f1.x; t0[5] = (bf16_t)f1.y; t0[6] = (bf16_t)f1.z; t0[7] = (bf16_t)f1.w;
    t1[0] = (bf16_t)f2.x; t1[1] = (bf16_t)f2.y; t1[2] = (bf16_t)f2.z; t1[3] = (bf16_t)f2.w;
    t1[4] = (bf16_t)f3.x; t1[5] = (bf16_t)f3.y; t1[6] = (bf16_t)f3.z; t1[7] = (bf16_t)f3.w;
    *(bf16x8v*)asw = t0;
    *(bf16x8v*)(asw + 8) = t1;
    __syncthreads();

    bf16x8v af[4], bfv[4];
#pragma unroll
    for (int i = 0; i < 4; ++i)
      af[i] = *(const bf16x8v*)(As + (wm * 64 + i * 16 + (lane & 15)) * 32 + (lane >> 4) * 8);
#pragma unroll
    for (int j = 0; j < 4; ++j)
      bfv[j] = *(const bf16x8v*)(Bs + (wn * 64 + j * 16 + (lane & 15)) * 32 + (lane >> 4) * 8);
#pragma unroll
    for (int i = 0; i < 4; ++i)
#pragma unroll
      for (int j = 0; j < 4; ++j)
        acc[i][j] = mfma16(af[i], bfv[j], acc[i][j]);
    __syncthreads();
  }

  if (p < 2) {
    bf16_t* Out = (p == 0) ? qb : kb;
#pragma unroll
    for (int i = 0; i < 4; ++i) {
      int mbase = m0 + wm * 64 + i * 16 + ((lane >> 4) << 2);
#pragma unroll
      for (int j = 0; j < 4; ++j) {
        int n = n0 + wn * 64 + j * 16 + (lane & 15);
        int h = n >> 6, hd = n & 63;
#pragma unroll
        for (int r = 0; r < 4; ++r) {
          int m = mbase + r;
          int b = m >> 11, t = m & 2047;
          Out[(((size_t)(b * 16 + h)) * 2048 + t) * 64 + hd] = (bf16_t)acc[i][j][r];
        }
      }
    }
  } else {
    // rows = n (head dims), cols = m (tokens): V^T layout (B,H,Hd,T)
#pragma unroll
    for (int i = 0; i < 4; ++i) {
      int nbase = n0 + wm * 64 + i * 16 + ((lane >> 4) << 2);
#pragma unroll
      for (int j = 0; j < 4; ++j) {
        int m = m0 + wn * 64 + j * 16 + (lane & 15);
        int b = m >> 11, t = m & 2047;
#pragma unroll
        for (int r = 0; r < 4; ++r) {
          int n = nbase + r;
          int h = n >> 6, hd = n & 63;
          vtb[((size_t)(b * 16 + h) * 64 + hd) * 2048 + t] = (bf16_t)acc[i][j][r];
        }
      }
    }
  }
}

// ---------------- causal flash attention ------------------------------------
// grid (16, 64): 128 q-rows/block, 4 waves x 32 q-rows. KVBLK=64.
// K (B,H,T,Hd) and V^T (B,H,Hd,T) staged via global_load_lds, XOR-swizzled
// source + swizzled ds_read (2-way conflicts). Double-buffered, 1 barrier/iter.
// Swapped QK^T; in-register P redistribution via 4x shfl_xor per window.
__global__ __launch_bounds__(256) void k_attn(
    const bf16_t* __restrict__ qb, const bf16_t* __restrict__ kb,
    const bf16_t* __restrict__ vtb, bf16_t* __restrict__ ob) {
  __shared__ __align__(16) bf16_t Ks[2][64 * 64];
  __shared__ __align__(16) bf16_t Vs[2][64 * 64];

  int bh = blockIdx.y;
  int qblk = gridDim.x - 1 - blockIdx.x;  // long blocks dispatch first
  int q0 = qblk * 128;
  int tid = threadIdx.x, lane = tid & 63, w = tid >> 6;
  int g = lane >> 4, qi = lane & 15;

  const bf16_t* Qp = qb + (size_t)bh * (2048 * 64);
  const bf16_t* Kp = kb + (size_t)bh * (2048 * 64);
  const bf16_t* Vp = vtb + (size_t)bh * (64 * 2048);

  int q0w = q0 + w * 32;

  bf16x8v qf[2][2];
#pragma unroll
  for (int qt = 0; qt < 2; ++qt)
#pragma unroll
    for (int kk = 0; kk < 2; ++kk)
      qf[qt][kk] = *(const bf16x8v*)(Qp + (size_t)(q0w + qt * 16 + qi) * 64 + kk * 32 + g * 8);

  f32x4v o[2][4] = {};
  float mrun[2] = {-1e30f, -1e30f};
  float lrun[2] = {0.f, 0.f};

  int nk = 2 * qblk + 2;

#define STAGE_KV(tt, bsel)                                                        \
  do {                                                                            \
    int kk0 = (tt) * 64;                                                          \
    _Pragma("unroll") for (int half = 0; half < 2; ++half) {                      \
      int row = w * 16 + half * 8 + (lane >> 3);                                  \
      int cc = ((lane & 7) ^ (row & 7)) << 3;                                     \
      gload_lds16(Kp + (size_t)(kk0 + row) * 64 + cc,                             \
                  &Ks[bsel][(w * 16 + half * 8) * 64]);                           \
      gload_lds16(Vp + (size_t)row * 2048 + kk0 + cc,                             \
                  &Vs[bsel][(w * 16 + half * 8) * 64]);                           \
    }                                                                             \
  } while (0)

  STAGE_KV(0, 0);
  __syncthreads();

  for (int t = 0; t < nk; ++t) {
    int bsel = t & 1;
    if (t + 1 < nk) {
      if (bsel) STAGE_KV(t + 1, 0); else STAGE_KV(t + 1, 1);
    }
    int k0 = t * 64;
    if (k0 <= q0w + 31) {
      const bf16_t* ks = Ks[bsel];
      const bf16_t* vs = Vs[bsel];
      // ---- QK^T (swapped): St[kt][qt], col=q, row=k
      f32x4v st[4][2];
      __builtin_amdgcn_s_setprio(1);
#pragma unroll
      for (int kt = 0; kt < 4; ++kt) {
        int r = kt * 16 + qi;
        bf16x8v kf0 = *(const bf16x8v*)(ks + r * 64 + (((0 + g) ^ (r & 7)) << 3));
        bf16x8v kf1 = *(const bf16x8v*)(ks + r * 64 + (((4 + g) ^ (r & 7)) << 3));
#pragma unroll
        for (int qt = 0; qt < 2; ++qt) {
          f32x4v z = {};
          z = mfma16(kf0, qf[qt][0], z);
          z = mfma16(kf1, qf[qt][1], z);
          st[kt][qt] = z;
        }
      }
      __builtin_amdgcn_s_setprio(0);

      // ---- causal mask (boundary tiles only)
      if (k0 + 63 > q0w) {
#pragma unroll
        for (int qt = 0; qt < 2; ++qt) {
          int qrow = q0w + qt * 16 + qi;
#pragma unroll
          for (int kt = 0; kt < 4; ++kt)
#pragma unroll
            for (int i = 0; i < 4; ++i) {
              int kg = k0 + kt * 16 + 4 * g + i;
              if (kg > qrow) st[kt][qt][i] = -1e30f;
            }
        }
      }

      // ---- online softmax (base-2, defer-max THR=8) + P exchange
      uint32_t paw[2][2][4];
#pragma unroll
      for (int qt = 0; qt < 2; ++qt) {
        float tmax = -1e30f;
#pragma unroll
        for (int kt = 0; kt < 4; ++kt)
#pragma unroll
          for (int i = 0; i < 4; ++i) tmax = fmaxf(tmax, st[kt][qt][i]);
        tmax = fmaxf(tmax, __shfl_xor(tmax, 16));
        tmax = fmaxf(tmax, __shfl_xor(tmax, 32));
        if (!__all(tmax - mrun[qt] <= 8.f)) {
          float mnew = fmaxf(mrun[qt], tmax);
          float sc = exp2f(mrun[qt] - mnew);
          lrun[qt] *= sc;
          mrun[qt] = mnew;
#pragma unroll
          for (int i = 0; i < 4; ++i) {
            float scb = __shfl(sc, (g << 2) + i);
#pragma unroll
            for (int dj = 0; dj < 4; ++dj) o[qt][dj][i] *= scb;
          }
        }
        float m = mrun[qt];
        float p_[4][4];
        float tsum = 0.f;
#pragma unroll
        for (int kt = 0; kt < 4; ++kt)
#pragma unroll
          for (int i = 0; i < 4; ++i) {
            float pv = exp2f(st[kt][qt][i] - m);
            p_[kt][i] = pv;
            tsum += pv;
          }
        tsum += __shfl_xor(tsum, 16);
        tsum += __shfl_xor(tsum, 32);
        lrun[qt] += tsum;

        // lane(g) holds P for q=qi at k=16*kt+4g+i; PA frag needs k=8g+j per
        // 32-wide window c. Two-step exchange: xor32 then xor16.
#pragma unroll
        for (int c = 0; c < 2; ++c) {
          uint32_t u0 = pk2(p_[2 * c][0], p_[2 * c][1]);
          uint32_t u1 = pk2(p_[2 * c][2], p_[2 * c][3]);
          uint32_t v0 = pk2(p_[2 * c + 1][0], p_[2 * c + 1][1]);
          uint32_t v1 = pk2(p_[2 * c + 1][2], p_[2 * c + 1][3]);
          bool lo = (g < 2);
          uint32_t o0 = lo ? u0 : v0, o1 = lo ? u1 : v1;
          uint32_t x0 = lo ? v0 : u0, x1 = lo ? v1 : u1;
          uint32_t r0 = (uint32_t)__shfl_xor((int)x0, 32);
          uint32_t r1 = (uint32_t)__shfl_xor((int)x1, 32);
          uint32_t P0 = lo ? o0 : r0, P1 = lo ? o1 : r1;
          uint32_t Q0 = lo ? r0 : o0, Q1 = lo ? r1 : o1;
          bool odd = (g & 1);
          uint32_t s0 = odd ? P0 : Q0, s1 = odd ? P1 : Q1;
          uint32_t y0 = (uint32_t)__shfl_xor((int)s0, 16);
          uint32_t y1 = (uint32_t)__shfl_xor((int)s1, 16);
          paw[qt][c][0] = odd ? y0 : P0;
          paw[qt][c][1] = odd ? y1 : P1;
          paw[qt][c][2] = odd ? Q0 : y0;
          paw[qt][c][3] = odd ? Q1 : y1;
        }
      }

      // ---- PV: O[q][d] += P * V  (V^T rows=d in LDS)
      __builtin_amdgcn_s_setprio(1);
#pragma unroll
      for (int dj = 0; dj < 4; ++dj) {
        int r = dj * 16 + qi;
#pragma unroll
        for (int c = 0; c < 2; ++c) {
          bf16x8v vf = *(const bf16x8v*)(vs + r * 64 + (((c * 4 + g) ^ (r & 7)) << 3));
#pragma unroll
          for (int qt = 0; qt < 2; ++qt) {
            union { uint32_t u[4]; bf16x8v v; } pa;
            pa.u[0] = paw[qt][c][0]; pa.u[1] = paw[qt][c][1];
            pa.u[2] = paw[qt][c][2]; pa.u[3] = paw[qt][c][3];
            o[qt][dj] = mfma16(pa.v, vf, o[qt][dj]);
          }
        }
      }
      __builtin_amdgcn_s_setprio(0);
    }
    __syncthreads();
  }

  // ---- epilogue: /l, write (B,T,D) bf16
  int b = bh >> 4, h = bh & 15;
#pragma unroll
  for (int qt = 0; qt < 2; ++qt) {
    float linv = 1.f / lrun[qt];
#pragma unroll
    for (int i = 0; i < 4; ++i) {
      float li = __shfl(linv, (g << 2) + i);
      int trow = q0w + qt * 16 + 4 * g + i;
      size_t base = ((size_t)(b * 2048 + trow)) * 1024 + h * 64;
#pragma unroll
      for (int dj = 0; dj < 4; ++dj)
        ob[base + dj * 16 + qi] = (bf16_t)(o[qt][dj][i] * li);
    }
  }
}

// ---------------- output projection GEMM (+bias, fp32 out) ------------------
__global__ __launch_bounds__(256) void k_oproj(
    const bf16_t* __restrict__ A, const bf16_t* __restrict__ Wo,
    const float* __restrict__ bo, float* __restrict__ out) {
  __shared__ __align__(16) bf16_t As[128 * 32];
  __shared__ __align__(16) bf16_t Bs[128 * 32];

  int n0 = blockIdx.x * 128;
  int m0 = blockIdx.y * 128;
  int tid = threadIdx.x, lane = tid & 63, wid = tid >> 6;
  int wm = wid >> 1, wn = wid & 1;

  f32x4v acc[4][4] = {};

  for (int k0 = 0; k0 < 1024; k0 += 32) {
#pragma unroll
    for (int j = 0; j < 2; ++j) {
      int c = (wid * 2 + j) * 64 + lane;
      gload_lds16(A + (size_t)(m0 + (c >> 2)) * 1024 + k0 + (c & 3) * 8,
                  (char*)As + (size_t)(wid * 2 + j) * 1024);
      gload_lds16(Wo + (size_t)(n0 + (c >> 2)) * 1024 + k0 + (c & 3) * 8,
                  (char*)Bs + (size_t)(wid * 2 + j) * 1024);
    }
    __syncthreads();

    bf16x8v af[4], bfv[4];
#pragma unroll
    for (int i = 0; i < 4; ++i)
      af[i] = *(const bf16x8v*)(As + (wm * 64 + i * 16 + (lane & 15)) * 32 + (lane >> 4) * 8);
#pragma unroll
    for (int j = 0; j < 4; ++j)
      bfv[j] = *(const bf16x8v*)(Bs + (wn * 64 + j * 16 + (lane & 15)) * 32 + (lane >> 4) * 8);
#pragma unroll
    for (int i = 0; i < 4; ++i)
#pragma unroll
      for (int j = 0; j < 4; ++j)
        acc[i][j] = mfma16(af[i], bfv[j], acc[i][j]);
    __syncthreads();
  }

#pragma unroll
  for (int i = 0; i < 4; ++i) {
    int mbase = m0 + wm * 64 + i * 16 + ((lane >> 4) << 2);
#pragma unroll
    for (int j = 0; j < 4; ++j) {
      int n = n0 + wn * 64 + j * 16 + (lane & 15);
      float bias = bo[n];
#pragma unroll
      for (int r = 0; r < 4; ++r) {
        int m = mbase + r;
        out[(size_t)m * 1024 + n] = acc[i][j][r] + bias;
      }
    }
  }
}

// ---------------- launch ----------------------------------------------------
extern "C" void kernel_launch(void* const* d_in, const int* in_sizes, int n_in,
                              void* d_out, int out_size, void* d_ws, size_t ws_size,
                              hipStream_t stream) {
  const float* querys = (const float*)d_in[0];
  const float* keys   = (const float*)d_in[1];
  const float* values = (const float*)d_in[2];
  const float* Wq = (const float*)d_in[3];
  const float* Wk = (const float*)d_in[4];
  const float* Wv = (const float*)d_in[5];
  const float* Wo = (const float*)d_in[6];
  const float* bo = (const float*)d_in[7];
  float* out = (float*)d_out;

  char* ws = (char*)d_ws;
  bf16_t* wb  = (bf16_t*)ws;                          // 8 MB
  bf16_t* qb  = (bf16_t*)(ws + ((size_t)8 << 20));    // 16 MB
  bf16_t* kb  = (bf16_t*)(ws + ((size_t)24 << 20));   // 16 MB
  bf16_t* vtb = (bf16_t*)(ws + ((size_t)40 << 20));   // 16 MB (B,H,Hd,T)
  bf16_t* ob  = (bf16_t*)(ws + ((size_t)56 << 20));   // 16 MB

  k_convw<<<4096, 256, 0, stream>>>(Wq, Wk, Wv, Wo, wb);
  k_qkv<<<dim3(8, 64, 3), 256, 0, stream>>>(querys, keys, values, wb, qb, kb, vtb);
  k_attn<<<dim3(16, 64), 256, 0, stream>>>(qb, kb, vtb, ob);
  k_oproj<<<dim3(8, 64), 256, 0, stream>>>(ob, wb + (size_t)3 * 1024 * 1024, bo, out);
}

// Round 3
// 363.877 us; speedup vs baseline: 1.5102x; 1.2646x over previous
//
#include <hip/hip_runtime.h>
#include <hip/hip_bf16.h>
#include <stdint.h>

typedef __bf16 bf16_t;
typedef __bf16 bf16x4v __attribute__((ext_vector_type(4)));
typedef __bf16 bf16x8v __attribute__((ext_vector_type(8)));
typedef float f32x4v __attribute__((ext_vector_type(4)));
typedef float f32x16v __attribute__((ext_vector_type(16)));

#define DEVI static __device__ __forceinline__

// B=4, T=2048, D=1024, H=16, Hd=64

DEVI f32x4v mfma16(bf16x8v a, bf16x8v b, f32x4v c) {
  return __builtin_amdgcn_mfma_f32_16x16x32_bf16(a, b, c, 0, 0, 0);
}
DEVI f32x16v mfma32(bf16x8v a, bf16x8v b, f32x16v c) {
  return __builtin_amdgcn_mfma_f32_32x32x16_bf16(a, b, c, 0, 0, 0);
}

DEVI void gload_lds16(const void* g, void* lds) {
  __builtin_amdgcn_global_load_lds(
      (const __attribute__((address_space(1))) uint32_t*)g,
      (__attribute__((address_space(3))) uint32_t*)lds, 16, 0, 0);
}

DEVI uint32_t pk2(float a, float b) {
  union { bf16_t h[2]; uint32_t u; } r;
  r.h[0] = (bf16_t)a;
  r.h[1] = (bf16_t)b;
  return r.u;
}

// ---------------- weight conversion -----------------------------------------
// Wq gets 0.125 (1/sqrt(64)) * log2(e) folded in (softmax via exp2).
__global__ void k_convw(const float* __restrict__ wq, const float* __restrict__ wk,
                        const float* __restrict__ wv, const float* __restrict__ wo,
                        bf16_t* __restrict__ out) {
  int i = blockIdx.x * 256 + threadIdx.x;
  int m = i >> 18;
  int off = (i & 0x3FFFF) << 2;
  const float* src = (m == 0) ? wq : (m == 1) ? wk : (m == 2) ? wv : wo;
  float4 v = *(const float4*)(src + off);
  float s = (m == 0) ? 0.18033688011112042f : 1.0f;  // 0.125 * log2(e)
  bf16x4v r;
  r[0] = (bf16_t)(v.x * s);
  r[1] = (bf16_t)(v.y * s);
  r[2] = (bf16_t)(v.z * s);
  r[3] = (bf16_t)(v.w * s);
  *(bf16x4v*)(out + ((size_t)i << 2)) = r;
}

// ---------------- QKV projection GEMM ---------------------------------------
// p<2  : C[m][n] = X W^T -> Q/K in (B,H,T,Hd)
// p==2 : operands swapped -> C'[n][m] = V^T in (B,H,Hd,T), coalesced writes
__global__ __launch_bounds__(256) void k_qkv(
    const float* __restrict__ q_in, const float* __restrict__ k_in,
    const float* __restrict__ v_in, const bf16_t* __restrict__ wb,
    bf16_t* __restrict__ qb, bf16_t* __restrict__ kb, bf16_t* __restrict__ vtb) {
  __shared__ __align__(16) bf16_t As[128 * 32];
  __shared__ __align__(16) bf16_t Bs[128 * 32];

  // XCD-chunked swizzle (nwg=1536, 192/XCD): same-m panels colocate per XCD
  int bid = blockIdx.x + (blockIdx.y << 3) + (blockIdx.z << 9);
  int swz = (bid & 7) * 192 + (bid >> 3);
  int p = swz >> 9;
  int n0 = (swz & 7) * 128;
  int m0 = ((swz >> 3) & 63) * 128;

  const float* X = (p == 0) ? q_in : (p == 1) ? k_in : v_in;
  const bf16_t* W = wb + (size_t)p * (1024 * 1024);

  int tid = threadIdx.x, lane = tid & 63, wid = tid >> 6;
  int wm = wid >> 1, wn = wid & 1;

  bf16_t* Xs = (p == 2) ? Bs : As;  // X rows (m-dim) go here
  bf16_t* Ws = (p == 2) ? As : Bs;  // W rows (n-dim) go here

  f32x4v acc[4][4] = {};

  int arow = tid >> 1, ahalf = tid & 1;
  const float* aptr = X + (size_t)(m0 + arow) * 1024 + ahalf * 16;
  bf16_t* asw = Xs + arow * 32 + ahalf * 16;

  for (int k0 = 0; k0 < 1024; k0 += 32) {
#pragma unroll
    for (int j = 0; j < 2; ++j) {
      int c = (wid * 2 + j) * 64 + lane;
      gload_lds16(W + (size_t)(n0 + (c >> 2)) * 1024 + k0 + (c & 3) * 8,
                  (char*)Ws + (size_t)(wid * 2 + j) * 1024);
    }
    float4 f0 = *(const float4*)(aptr + k0);
    float4 f1 = *(const float4*)(aptr + k0 + 4);
    float4 f2 = *(const float4*)(aptr + k0 + 8);
    float4 f3 = *(const float4*)(aptr + k0 + 12);
    bf16x8v t0, t1;
    t0[0] = (bf16_t)f0.x; t0[1] = (bf16_t)f0.y; t0[2] = (bf16_t)f0.z; t0[3] = (bf16_t)f0.w;
    t0[4] = (bf16_t)f1.x; t0[5] = (bf16_t)f1.y; t0[6] = (bf16_t)f1.z; t0[7] = (bf16_t)f1.w;
    t1[0] = (bf16_t)f2.x; t1[1] = (bf16_t)f2.y; t1[2] = (bf16_t)f2.z; t1[3] = (bf16_t)f2.w;
    t1[4] = (bf16_t)f3.x; t1[5] = (bf16_t)f3.y; t1[6] = (bf16_t)f3.z; t1[7] = (bf16_t)f3.w;
    *(bf16x8v*)asw = t0;
    *(bf16x8v*)(asw + 8) = t1;
    __syncthreads();

    bf16x8v af[4], bfv[4];
#pragma unroll
    for (int i = 0; i < 4; ++i)
      af[i] = *(const bf16x8v*)(As + (wm * 64 + i * 16 + (lane & 15)) * 32 + (lane >> 4) * 8);
#pragma unroll
    for (int j = 0; j < 4; ++j)
      bfv[j] = *(const bf16x8v*)(Bs + (wn * 64 + j * 16 + (lane & 15)) * 32 + (lane >> 4) * 8);
#pragma unroll
    for (int i = 0; i < 4; ++i)
#pragma unroll
      for (int j = 0; j < 4; ++j)
        acc[i][j] = mfma16(af[i], bfv[j], acc[i][j]);
    __syncthreads();
  }

  if (p < 2) {
    bf16_t* Out = (p == 0) ? qb : kb;
#pragma unroll
    for (int i = 0; i < 4; ++i) {
      int mbase = m0 + wm * 64 + i * 16 + ((lane >> 4) << 2);
#pragma unroll
      for (int j = 0; j < 4; ++j) {
        int n = n0 + wn * 64 + j * 16 + (lane & 15);
        int h = n >> 6, hd = n & 63;
#pragma unroll
        for (int r = 0; r < 4; ++r) {
          int m = mbase + r;
          int b = m >> 11, t = m & 2047;
          Out[(((size_t)(b * 16 + h)) * 2048 + t) * 64 + hd] = (bf16_t)acc[i][j][r];
        }
      }
    }
  } else {
    // rows = n (head dims), cols = m (tokens): V^T layout (B,H,Hd,T)
#pragma unroll
    for (int i = 0; i < 4; ++i) {
      int nbase = n0 + wm * 64 + i * 16 + ((lane >> 4) << 2);
#pragma unroll
      for (int j = 0; j < 4; ++j) {
        int m = m0 + wn * 64 + j * 16 + (lane & 15);
        int b = m >> 11, t = m & 2047;
#pragma unroll
        for (int r = 0; r < 4; ++r) {
          int n = nbase + r;
          int h = n >> 6, hd = n & 63;
          vtb[((size_t)(b * 16 + h) * 64 + hd) * 2048 + t] = (bf16_t)acc[i][j][r];
        }
      }
    }
  }
}

// ---------------- causal flash attention (32x32 MFMA, 3-buf pipeline) -------
// grid (8, 64): block handles paired q-supertiles (j, 15-j), 128 rows each,
// 4 waves x 32 q-rows. KVBLK=64. Uniform 36 k-tiles/block.
// 3 LDS buffers, prefetch 2 ahead, raw s_barrier + counted vmcnt (T3+T4).
// Swapped QK^T (32x32): P^T col=q=lane&31, row k=(reg&3)+8*(reg>>2)+4*hi.
// P -> PV A-frag via 8 pk2 + 4 shfl_xor(32) per 32-k block (T12 analog).
__global__ __launch_bounds__(256) void k_attn(
    const bf16_t* __restrict__ qb, const bf16_t* __restrict__ kb,
    const bf16_t* __restrict__ vtb, bf16_t* __restrict__ ob) {
  __shared__ __align__(16) bf16_t Ks[3][64 * 64];
  __shared__ __align__(16) bf16_t Vs[3][64 * 64];

  // XCD swizzle: same-bh blocks colocate (K/V L2 reuse). nwg=512, 64/XCD.
  int bid = blockIdx.x + (blockIdx.y << 3);
  int swz = (bid & 7) * 64 + (bid >> 3);
  int xpair = swz & 7;
  int bh = swz >> 3;

  int tid = threadIdx.x, lane = tid & 63, w = tid >> 6;
  int hi = lane >> 5, q = lane & 31;

  const bf16_t* Qp = qb + (size_t)bh * (2048 * 64);
  const bf16_t* Kp = kb + (size_t)bh * (2048 * 64);
  const bf16_t* Vp = vtb + (size_t)bh * (64 * 2048);

#define STAGE(tt, bsel)                                                \
  do {                                                                 \
    int kk0 = (tt) * 64;                                               \
    _Pragma("unroll") for (int half = 0; half < 2; ++half) {           \
      int row = w * 16 + half * 8 + (lane >> 3);                       \
      int cc = ((lane & 7) ^ (row & 7)) << 3;                          \
      gload_lds16(Kp + (size_t)(kk0 + row) * 64 + cc,                  \
                  &Ks[bsel][(w * 16 + half * 8) * 64]);                \
      gload_lds16(Vp + (size_t)row * 2048 + kk0 + cc,                  \
                  &Vs[bsel][(w * 16 + half * 8) * 64]);                \
    }                                                                  \
  } while (0)

  int b_ = bh >> 4, h_ = bh & 15;

#pragma unroll 1
  for (int ph = 0; ph < 2; ++ph) {
    int j = ph ? (15 - xpair) : xpair;
    int q0w = j * 128 + w * 32;
    int nk = 2 * j + 2;

    // Q fragments: qf[dd] = Q[q0w+q][dd*16 + hi*8 .. +8]
    bf16x8v qf[4];
#pragma unroll
    for (int dd = 0; dd < 4; ++dd)
      qf[dd] = *(const bf16x8v*)(Qp + (size_t)(q0w + q) * 64 + dd * 16 + hi * 8);

    f32x16v o0 = {}, o1 = {};
    float mrun = -1e30f, lrun = 0.f;

    STAGE(0, 0);
    STAGE(1, 1);

#pragma unroll 1
    for (int t = 0; t < nk; ++t) {
      int bsel = t % 3;
      if (t + 1 < nk) {
        asm volatile("s_waitcnt vmcnt(4)" ::: "memory");  // tile t done, t+1 in flight
      } else {
        asm volatile("s_waitcnt vmcnt(0)" ::: "memory");
      }
      __builtin_amdgcn_s_barrier();
      if (t + 2 < nk) STAGE(t + 2, (t + 2) % 3);

      int k0 = t * 64;
      if (k0 <= q0w + 31) {
        const bf16_t* ks = Ks[bsel];
        const bf16_t* vs = Vs[bsel];

        // ---- QK^T swapped: st[kb] = S^T tile, col=q, row=k_local
        f32x16v st[2];
        __builtin_amdgcn_s_setprio(1);
#pragma unroll
        for (int kb = 0; kb < 2; ++kb) {
          int r = kb * 32 + q;
          f32x16v z = {};
#pragma unroll
          for (int dd = 0; dd < 4; ++dd) {
            bf16x8v kf = *(const bf16x8v*)(ks + r * 64 + (((dd * 2 + hi) ^ (r & 7)) << 3));
            z = mfma32(kf, qf[dd], z);
          }
          st[kb] = z;
        }
        __builtin_amdgcn_s_setprio(0);

        // ---- causal mask (boundary tiles only)
        if (k0 + 63 > q0w) {
          int qrow = q0w + q;
#pragma unroll
          for (int kb = 0; kb < 2; ++kb)
#pragma unroll
            for (int reg = 0; reg < 16; ++reg) {
              int kg = k0 + kb * 32 + (reg & 3) + 8 * (reg >> 2) + 4 * hi;
              if (kg > qrow) st[kb][reg] = -1e30f;
            }
        }

        // ---- online softmax (base-2, defer-max THR=8)
        float tmax = -1e30f;
#pragma unroll
        for (int kb = 0; kb < 2; ++kb)
#pragma unroll
          for (int reg = 0; reg < 16; ++reg) tmax = fmaxf(tmax, st[kb][reg]);
        tmax = fmaxf(tmax, __shfl_xor(tmax, 32));
        if (!__all(tmax - mrun <= 8.f)) {
          float mnew = fmaxf(mrun, tmax);
          float sc = exp2f(mrun - mnew);
          lrun *= sc;
          mrun = mnew;
#pragma unroll
          for (int reg = 0; reg < 16; ++reg) {
            float scb = __shfl(sc, (reg & 3) + 8 * (reg >> 2) + 4 * hi);
            o0[reg] *= scb;
            o1[reg] *= scb;
          }
        }

        float p_[32];
        float tsum = 0.f;
#pragma unroll
        for (int kb = 0; kb < 2; ++kb)
#pragma unroll
          for (int reg = 0; reg < 16; ++reg) {
            float pv = exp2f(st[kb][reg] - mrun);
            p_[kb * 16 + reg] = pv;
            tsum += pv;
          }
        tsum += __shfl_xor(tsum, 32);
        lrun += tsum;

        // ---- P^T -> PV A-frags: pa[ks] holds P[q][ks*16 + hi*8 .. +8]
        uint32_t pa[4][4];
#pragma unroll
        for (int kb = 0; kb < 2; ++kb) {
          uint32_t a0 = pk2(p_[kb * 16 + 0], p_[kb * 16 + 1]);
          uint32_t a1 = pk2(p_[kb * 16 + 2], p_[kb * 16 + 3]);
          uint32_t b0 = pk2(p_[kb * 16 + 4], p_[kb * 16 + 5]);
          uint32_t b1 = pk2(p_[kb * 16 + 6], p_[kb * 16 + 7]);
          uint32_t a2 = pk2(p_[kb * 16 + 8], p_[kb * 16 + 9]);
          uint32_t a3 = pk2(p_[kb * 16 + 10], p_[kb * 16 + 11]);
          uint32_t b2 = pk2(p_[kb * 16 + 12], p_[kb * 16 + 13]);
          uint32_t b3 = pk2(p_[kb * 16 + 14], p_[kb * 16 + 15]);
          uint32_t s0 = hi ? a0 : b0, s1 = hi ? a1 : b1;
          uint32_t s2 = hi ? a2 : b2, s3 = hi ? a3 : b3;
          uint32_t r0 = (uint32_t)__shfl_xor((int)s0, 32);
          uint32_t r1 = (uint32_t)__shfl_xor((int)s1, 32);
          uint32_t r2 = (uint32_t)__shfl_xor((int)s2, 32);
          uint32_t r3 = (uint32_t)__shfl_xor((int)s3, 32);
          pa[2 * kb + 0][0] = hi ? r0 : a0;
          pa[2 * kb + 0][1] = hi ? r1 : a1;
          pa[2 * kb + 0][2] = hi ? b0 : r0;
          pa[2 * kb + 0][3] = hi ? b1 : r1;
          pa[2 * kb + 1][0] = hi ? r2 : a2;
          pa[2 * kb + 1][1] = hi ? r3 : a3;
          pa[2 * kb + 1][2] = hi ? b2 : r2;
          pa[2 * kb + 1][3] = hi ? b3 : r3;
        }

        // ---- PV: O[q][d], A=P (rows q), B=V^T (rows d)
        __builtin_amdgcn_s_setprio(1);
#pragma unroll
        for (int dt = 0; dt < 2; ++dt) {
          int r = dt * 32 + q;
#pragma unroll
          for (int ks2 = 0; ks2 < 4; ++ks2) {
            bf16x8v vf = *(const bf16x8v*)(vs + r * 64 + (((ks2 * 2 + hi) ^ (r & 7)) << 3));
            union { uint32_t u[4]; bf16x8v v; } pav;
            pav.u[0] = pa[ks2][0]; pav.u[1] = pa[ks2][1];
            pav.u[2] = pa[ks2][2]; pav.u[3] = pa[ks2][3];
            if (dt == 0) o0 = mfma32(pav.v, vf, o0);
            else         o1 = mfma32(pav.v, vf, o1);
          }
        }
        __builtin_amdgcn_s_setprio(0);
      }
    }

    // ---- epilogue: /l, write (B,T,D) bf16
    float linv = 1.f / lrun;
#pragma unroll
    for (int reg = 0; reg < 16; ++reg) {
      int qr = (reg & 3) + 8 * (reg >> 2) + 4 * hi;
      float li = __shfl(linv, qr);
      int trow = q0w + qr;
      size_t base = ((size_t)(b_ * 2048 + trow)) * 1024 + h_ * 64;
      ob[base + q] = (bf16_t)(o0[reg] * li);
      ob[base + 32 + q] = (bf16_t)(o1[reg] * li);
    }
    __builtin_amdgcn_s_barrier();  // protect next phase's restage
  }
#undef STAGE
}

// ---------------- output projection GEMM (+bias, fp32 out) ------------------
__global__ __launch_bounds__(256) void k_oproj(
    const bf16_t* __restrict__ A, const bf16_t* __restrict__ Wo,
    const float* __restrict__ bo, float* __restrict__ out) {
  __shared__ __align__(16) bf16_t As[128 * 32];
  __shared__ __align__(16) bf16_t Bs[128 * 32];

  int bid = blockIdx.x + (blockIdx.y << 3);
  int swz = (bid & 7) * 64 + (bid >> 3);
  int n0 = (swz & 7) * 128;
  int m0 = (swz >> 3) * 128;

  int tid = threadIdx.x, lane = tid & 63, wid = tid >> 6;
  int wm = wid >> 1, wn = wid & 1;

  f32x4v acc[4][4] = {};

  for (int k0 = 0; k0 < 1024; k0 += 32) {
#pragma unroll
    for (int j = 0; j < 2; ++j) {
      int c = (wid * 2 + j) * 64 + lane;
      gload_lds16(A + (size_t)(m0 + (c >> 2)) * 1024 + k0 + (c & 3) * 8,
                  (char*)As + (size_t)(wid * 2 + j) * 1024);
      gload_lds16(Wo + (size_t)(n0 + (c >> 2)) * 1024 + k0 + (c & 3) * 8,
                  (char*)Bs + (size_t)(wid * 2 + j) * 1024);
    }
    __syncthreads();

    bf16x8v af[4], bfv[4];
#pragma unroll
    for (int i = 0; i < 4; ++i)
      af[i] = *(const bf16x8v*)(As + (wm * 64 + i * 16 + (lane & 15)) * 32 + (lane >> 4) * 8);
#pragma unroll
    for (int j = 0; j < 4; ++j)
      bfv[j] = *(const bf16x8v*)(Bs + (wn * 64 + j * 16 + (lane & 15)) * 32 + (lane >> 4) * 8);
#pragma unroll
    for (int i = 0; i < 4; ++i)
#pragma unroll
      for (int j = 0; j < 4; ++j)
        acc[i][j] = mfma16(af[i], bfv[j], acc[i][j]);
    __syncthreads();
  }

#pragma unroll
  for (int i = 0; i < 4; ++i) {
    int mbase = m0 + wm * 64 + i * 16 + ((lane >> 4) << 2);
#pragma unroll
    for (int j = 0; j < 4; ++j) {
      int n = n0 + wn * 64 + j * 16 + (lane & 15);
      float bias = bo[n];
#pragma unroll
      for (int r = 0; r < 4; ++r) {
        int m = mbase + r;
        out[(size_t)m * 1024 + n] = acc[i][j][r] + bias;
      }
    }
  }
}

// ---------------- launch ----------------------------------------------------
extern "C" void kernel_launch(void* const* d_in, const int* in_sizes, int n_in,
                              void* d_out, int out_size, void* d_ws, size_t ws_size,
                              hipStream_t stream) {
  const float* querys = (const float*)d_in[0];
  const float* keys   = (const float*)d_in[1];
  const float* values = (const float*)d_in[2];
  const float* Wq = (const float*)d_in[3];
  const float* Wk = (const float*)d_in[4];
  const float* Wv = (const float*)d_in[5];
  const float* Wo = (const float*)d_in[6];
  const float* bo = (const float*)d_in[7];
  float* out = (float*)d_out;

  char* ws = (char*)d_ws;
  bf16_t* wb  = (bf16_t*)ws;                          // 8 MB
  bf16_t* qb  = (bf16_t*)(ws + ((size_t)8 << 20));    // 16 MB
  bf16_t* kb  = (bf16_t*)(ws + ((size_t)24 << 20));   // 16 MB
  bf16_t* vtb = (bf16_t*)(ws + ((size_t)40 << 20));   // 16 MB (B,H,Hd,T)
  bf16_t* ob  = (bf16_t*)(ws + ((size_t)56 << 20));   // 16 MB

  k_convw<<<4096, 256, 0, stream>>>(Wq, Wk, Wv, Wo, wb);
  k_qkv<<<dim3(8, 64, 3), 256, 0, stream>>>(querys, keys, values, wb, qb, kb, vtb);
  k_attn<<<dim3(8, 64), 256, 0, stream>>>(qb, kb, vtb, ob);
  k_oproj<<<dim3(8, 64), 256, 0, stream>>>(ob, wb + (size_t)3 * 1024 * 1024, bo, out);
}